// Round 11
// baseline (108.243 us; speedup 1.0000x reference)
//
#include <hip/hip_runtime.h>
#include <hip/hip_bf16.h>

#define B_ 8
#define N_ 512
#define D_ 512
#define H_ 8
#define DK_ 64

// 1000^(-f/8), f=0..7 (double-evaluated, f32-rounded)
__device__ constexpr float DMc[8] = {
    1.0f, 0.42169650342905464f, 0.1778279410038923f, 0.07498942093324559f,
    0.03162277660168379f, 0.013335214321633241f, 0.005623413251903491f,
    0.0023713737056616554f};

__device__ inline float bf2f(unsigned short u) {
    unsigned int x = ((unsigned int)u) << 16;
    return __uint_as_float(x);
}

typedef __attribute__((ext_vector_type(8))) short bf8v;
typedef __attribute__((ext_vector_type(4))) float f4v;

union AFrag { bf8v v; unsigned int u[4]; uint2 d[2]; };

__device__ inline unsigned int cvt_pk_bf16(float a, float b) {
    unsigned int r;
    asm("v_cvt_pk_bf16_f32 %0, %1, %2" : "=v"(r) : "v"(a), "v"(b));
    return r;  // bits[15:0]=bf16(a), bits[31:16]=bf16(b)
}

// x = hi + lo (both bf16), fp32-accurate reconstruction for split-MFMA
__device__ inline void split_pair(float a, float b, unsigned int& uhi, unsigned int& ulo) {
    const unsigned int uh = cvt_pk_bf16(a, b);
    const float ah = __uint_as_float(uh << 16);
    const float bh = __uint_as_float(uh & 0xFFFF0000u);
    ulo = cvt_pk_bf16(a - ah, b - bh);
    uhi = uh;
}

// ---------------------------------------------------------------------------
// K0: pre-convert weights to frag-major planes (W only — X converts in-lane
// inside k_mix now).
// z=0,1 (Wq,Wk): bf16 plane [nt32][ks16][g4][row16][8] -> whl + z*262144.
// z=2,3 (Wv,Wo): hi/lo planes [nt32][ks16][g4][hl2][row16][8] -> whl+524288+...
// ---------------------------------------------------------------------------
__global__ __launch_bounds__(256) void k_split_w(
    const float* __restrict__ Wq, const float* __restrict__ Wk,
    const float* __restrict__ Wv, const float* __restrict__ Wo,
    unsigned short* __restrict__ whl)
{
    const int z = blockIdx.y;
    const float* W = (z == 0) ? Wq : (z == 1) ? Wk : (z == 2) ? Wv : Wo;

    const int nt = blockIdx.x;        // ntile 0..31
    const int t = threadIdx.x;
    const int row = t >> 4;           // 0..15
    const int ks = t & 15;

    const float* wsrc = W + (size_t)(nt * 16 + row) * 512 + ks * 32;
    float e[32];
#pragma unroll
    for (int i = 0; i < 8; ++i) {
        const float4 v4 = *(const float4*)(wsrc + 4 * i);
        e[4 * i] = v4.x; e[4 * i + 1] = v4.y; e[4 * i + 2] = v4.z; e[4 * i + 3] = v4.w;
    }

    if (z < 2) {
        unsigned short* out = whl + (size_t)z * 262144;
#pragma unroll
        for (int g = 0; g < 4; ++g) {
            const unsigned int u0 = cvt_pk_bf16(e[4 * g + 0], e[4 * g + 1]);
            const unsigned int u1 = cvt_pk_bf16(e[4 * g + 2], e[4 * g + 3]);
            const unsigned int u2 = cvt_pk_bf16(e[16 + 4 * g + 0], e[16 + 4 * g + 1]);
            const unsigned int u3 = cvt_pk_bf16(e[16 + 4 * g + 2], e[16 + 4 * g + 3]);
            const size_t base = ((size_t)((nt * 16 + ks) * 4 + g)) * 128 + row * 8;
            *(uint4*)(out + base) = make_uint4(u0, u1, u2, u3);
        }
    } else {
        unsigned short* out = whl + 524288 + (size_t)(z - 2) * 524288;
#pragma unroll
        for (int g = 0; g < 4; ++g) {
            unsigned int h0, l0, h1, l1, h2, l2, h3, l3;
            split_pair(e[4 * g + 0], e[4 * g + 1], h0, l0);
            split_pair(e[4 * g + 2], e[4 * g + 3], h1, l1);
            split_pair(e[16 + 4 * g + 0], e[16 + 4 * g + 1], h2, l2);
            split_pair(e[16 + 4 * g + 2], e[16 + 4 * g + 3], h3, l3);
            const size_t base = ((size_t)(nt * 16 + ks) * 8 + g * 2) * 128 + row * 8;
            *(uint4*)(out + base) = make_uint4(h0, h1, h2, h3);
            *(uint4*)(out + base + 128) = make_uint4(l0, l1, l2, l3);
        }
    }
}

// ---------------------------------------------------------------------------
// K1 (v4): MERGED qkv-GEMM + box-gate. Grid 4864 = 256 groups x 19.
// gemm path: BARRIER-FREE, LDS-FREE. A frags converted in-lane from f32 X
// (two float4 loads + 4 cvt_pk per frag; 64B-contiguous per 4-lane row group,
// L2-reused 4x across n0 blocks). B frags from whl planes. q/k: 1 MFMA/frag;
// v: 2-term W-side split.
// wgc path: reg-hoisted S reads, __sincosf.
// LB(256,6): measured VGPR_Count=40 at LB4 -> cap 85 has headroom (r8's spill
// was a ~100-VGPR kernel at the same cap). Tripwire: WRITE_SIZE >> 45MB.
// ---------------------------------------------------------------------------
__global__ __launch_bounds__(256, 6) void k_mix(
    const float* __restrict__ Xq, const float* __restrict__ Xk, const float* __restrict__ Xv,
    const unsigned short* __restrict__ whl,
    const float* __restrict__ bq, const float* __restrict__ bk, const float* __restrict__ bv,
    unsigned short* __restrict__ oq, unsigned short* __restrict__ ok,
    unsigned short* __restrict__ ov,
    const float* __restrict__ box, const float* __restrict__ WGw,
    const float* __restrict__ WGb, unsigned short* __restrict__ wgc)
{
    __shared__ float S[4][520];   // wgc path only (8320B)

    const int bid = blockIdx.x;
    const int grp = bid / 19;
    const int r19 = bid - grp * 19;
    const int t = threadIdx.x;

    if (r19 < 3) {
        // ---------------- GEMM path (no LDS, no barriers) ----------------
        const int zz = r19;
        const int mn = grp;                 // 0..255
        const int m0 = (mn & 63) * 64;
        const int n0 = (mn >> 6) * 128;

        const float* X = (zz == 0) ? Xq : (zz == 1) ? Xk : Xv;
        const float* bias = (zz == 0) ? bq : (zz == 1) ? bk : bv;
        const unsigned short* wp = whl + ((zz == 2) ? 524288 : (size_t)zz * 262144);
        const bool vsplit = (zz == 2);

        const int lane = t & 63;
        const int wv = t >> 6;
        const int cl = lane & 15, g = lane >> 4;
        const int wr = wv >> 1, wc = wv & 1;

        f4v acc[2][4];
#pragma unroll
        for (int i = 0; i < 2; ++i)
#pragma unroll
            for (int j = 0; j < 4; ++j) acc[i][j] = (f4v){0.f, 0.f, 0.f, 0.f};

        const int ntb = (n0 >> 4) + wc * 4;
        const int mt0 = (m0 >> 4) + wr * 2;

        for (int k0 = 0; k0 < 512; k0 += 64) {
#pragma unroll
            for (int ks = 0; ks < 2; ++ks) {
                const int kidx = (k0 >> 5) + ks;
                AFrag ah[2];
#pragma unroll
                for (int mt = 0; mt < 2; ++mt) {
                    const float* xrow = X + (size_t)((mt0 + mt) * 16 + cl) * 512 +
                                        kidx * 32 + 4 * g;
                    const float4 x0 = *(const float4*)xrow;
                    const float4 x1 = *(const float4*)(xrow + 16);
                    ah[mt].u[0] = cvt_pk_bf16(x0.x, x0.y);
                    ah[mt].u[1] = cvt_pk_bf16(x0.z, x0.w);
                    ah[mt].u[2] = cvt_pk_bf16(x1.x, x1.y);
                    ah[mt].u[3] = cvt_pk_bf16(x1.z, x1.w);
                }
#pragma unroll
                for (int nt = 0; nt < 4; ++nt) {
                    AFrag bh, bl;
                    if (vsplit) {
                        const size_t be = ((size_t)((ntb + nt) * 16 + kidx) * 8 + g * 2) * 128 +
                                          cl * 8;
                        bh.v = *(const bf8v*)(wp + be);
                        bl.v = *(const bf8v*)(wp + be + 128);
                    } else {
                        const size_t be = ((size_t)((ntb + nt) * 16 + kidx) * 4 + g) * 128 +
                                          cl * 8;
                        bh.v = *(const bf8v*)(wp + be);
                    }
#pragma unroll
                    for (int mt = 0; mt < 2; ++mt) {
                        acc[mt][nt] = __builtin_amdgcn_mfma_f32_16x16x32_bf16(
                            ah[mt].v, bh.v, acc[mt][nt], 0, 0, 0);
                        if (vsplit)
                            acc[mt][nt] = __builtin_amdgcn_mfma_f32_16x16x32_bf16(
                                ah[mt].v, bl.v, acc[mt][nt], 0, 0, 0);
                    }
                }
            }
        }

        const int mbase = m0 + wr * 32;
        const int nb = n0 + wc * 64;

        if (zz == 2) {
#pragma unroll
            for (int mt = 0; mt < 2; ++mt) {
#pragma unroll
                for (int nt = 0; nt < 4; ++nt) {
                    const int m = mbase + mt * 16 + 4 * g;
                    const int n = nb + nt * 16 + cl;
                    const float bb = bias[n];
                    uint2 pk;
                    pk.x = cvt_pk_bf16(acc[mt][nt][0] + bb, acc[mt][nt][1] + bb);
                    pk.y = cvt_pk_bf16(acc[mt][nt][2] + bb, acc[mt][nt][3] + bb);
                    *(uint2*)&ov[(((size_t)(m >> 9) * 8 + (n >> 6)) * 64 + (n & 63)) * 512 +
                                 (m & 511)] = pk;
                }
            }
        } else {
            unsigned short* outp = (zz == 0) ? oq : ok;
            const float sc = (zz == 0) ? 0.125f : 1.0f;
#pragma unroll
            for (int mt = 0; mt < 2; ++mt) {
#pragma unroll
                for (int nt = 0; nt < 4; ++nt) {
                    const int n = nb + nt * 16 + cl;
                    const float bb = bias[n];
#pragma unroll
                    for (int r = 0; r < 4; ++r) {
                        const int m = mbase + mt * 16 + 4 * g + r;
                        outp[(((size_t)(m >> 9) * 8 + (n >> 6)) * 512 + (m & 511)) * 64 +
                             (n & 63)] =
                            (unsigned short)cvt_pk_bf16((acc[mt][nt][r] + bb) * sc, 0.f);
                    }
                }
            }
        }
    } else {
        // ---------------- WGC path ----------------
        const int wb = grp * 16 + (r19 - 3);   // 0..4095
        const int n = wb & 511;
        const int b = wb >> 9;

        for (int mi = t; mi < 512; mi += 256) {
            const float4 bx = *(const float4*)&box[(size_t)(b * N_ + mi) * 4];
            S[0][mi] = (bx.x + bx.z) * 0.5f;
            S[1][mi] = (bx.y + bx.w) * 0.5f;
            S[2][mi] = __logf(bx.z - bx.x + 1.0f);
            S[3][mi] = __logf(bx.w - bx.y + 1.0f);
        }

        const float4 bn = *(const float4*)&box[(size_t)(b * N_ + n) * 4];
        const float wn = bn.z - bn.x + 1.0f;
        const float hn = bn.w - bn.y + 1.0f;
        const float rwn = 1.0f / wn;
        const float rhn = 1.0f / hn;
        const float cxn = (bn.x + bn.z) * 0.5f;
        const float cyn = (bn.y + bn.w) * 0.5f;
        const float lwn = __logf(wn);
        const float lhn = __logf(hn);

        const int lane = t & 63;
        const int col = lane & 15;
        const int grp2 = lane >> 4;
        const int w = t >> 6;

        AFrag bs, bc;
        if (col < 8) {
            const float* wr2 = WGw + col * 64 + grp2 * 8;
#pragma unroll
            for (int j = 0; j < 4; ++j) {
                bs.u[j] = cvt_pk_bf16(wr2[2 * j], wr2[2 * j + 1]);
                bc.u[j] = cvt_pk_bf16(wr2[32 + 2 * j], wr2[32 + 2 * j + 1]);
            }
        } else {
#pragma unroll
            for (int j = 0; j < 4; ++j) { bs.u[j] = 0u; bc.u[j] = 0u; }
        }
        const float bias = (col < 8) ? WGb[col] : 0.0f;

        const float dn = (grp2 == 0) ? cxn : (grp2 == 1) ? cyn : (grp2 == 2) ? lwn : lhn;
        const float rA = (grp2 == 0) ? rwn : rhn;

        unsigned short* outb = (col < 8)
            ? wgc + ((size_t)(b * H_ + col) * N_ + n) * N_ : wgc;

        __syncthreads();

        // hoist: this lane's 8 table values -> registers; loop is memory-free
        float svr[8];
#pragma unroll
        for (int mt = 0; mt < 8; ++mt) svr[mt] = S[grp2][mt * 64 + w * 16 + col];

#pragma unroll
        for (int mt = 0; mt < 8; ++mt) {
            const int m0 = mt * 64 + w * 16;

            const float diff = dn - svr[mt];
            const float posA = __logf(fmaxf(fabsf(diff) * rA, 1e-3f));
            const float pos = (grp2 < 2) ? posA : diff;
            const float p100 = 100.0f * pos;

            float sn[8], cs[8];
#pragma unroll
            for (int j = 0; j < 8; ++j) {
                __sincosf(p100 * DMc[j], &sn[j], &cs[j]);
            }
            AFrag as_, ac_;
#pragma unroll
            for (int j = 0; j < 4; ++j) {
                as_.u[j] = cvt_pk_bf16(sn[2 * j], sn[2 * j + 1]);
                ac_.u[j] = cvt_pk_bf16(cs[2 * j], cs[2 * j + 1]);
            }

            f4v acc = __builtin_amdgcn_mfma_f32_16x16x32_bf16(
                as_.v, bs.v, (f4v){0.f, 0.f, 0.f, 0.f}, 0, 0, 0);
            acc = __builtin_amdgcn_mfma_f32_16x16x32_bf16(ac_.v, bc.v, acc, 0, 0, 0);

            if (col < 8) {
                const int mrow = m0 + grp2 * 4;
                const float v0 = fmaxf(acc[0] + bias, 1e-6f);
                const float v1 = fmaxf(acc[1] + bias, 1e-6f);
                const float v2 = fmaxf(acc[2] + bias, 1e-6f);
                const float v3 = fmaxf(acc[3] + bias, 1e-6f);
                uint2 pk;
                pk.x = cvt_pk_bf16(v0, v1);
                pk.y = cvt_pk_bf16(v2, v3);
                *(uint2*)&outb[mrow] = pk;
            }
        }
    }
}

// ---------------------------------------------------------------------------
// K4: output projection, 32x128 tiles, 3-term split (unchanged).
// ---------------------------------------------------------------------------
__global__ __launch_bounds__(256, 2) void k_gemm_o(
    const float* __restrict__ AO, const unsigned short* __restrict__ whl,
    const float* __restrict__ bias, float* __restrict__ outp)
{
    const unsigned short* wp = whl + 1048576;   // Wo hi/lo plane

    const int m0 = blockIdx.x * 32;
    const int n0 = blockIdx.y * 128;
    __shared__ __align__(16) short Al[4096];    // [ks2][mt2][g4][hl2][row16][8]
    const int t = threadIdx.x;
    const int lane = t & 63;
    const int wv = t >> 6;
    const int cl = lane & 15, g = lane >> 4;
    const int wr = wv >> 1, wc = wv & 1;

    const int srow = t >> 3;        // 0..31
    const int skq = t & 7;
    const int ksub = skq >> 2;
    const int half = (skq >> 1) & 1;
    const int g2b = (skq & 1) * 2;
    const float* xp = AO + (size_t)(m0 + srow) * 512 + skq * 8;
    short* alw = Al + ksub * 2048 + (srow >> 4) * 1024 + (srow & 15) * 8 + half * 4;

    f4v acc[4];
#pragma unroll
    for (int j = 0; j < 4; ++j) acc[j] = (f4v){0.f, 0.f, 0.f, 0.f};
    const int ntb = (n0 >> 4) + wc * 4;

    for (int k0 = 0; k0 < 512; k0 += 64) {
        float4 xl0 = *(const float4*)(xp + k0);
        float4 xl1 = *(const float4*)(xp + k0 + 4);

        AFrag bh0[4], bl0[4];
#pragma unroll
        for (int nt = 0; nt < 4; ++nt) {
            const size_t be = ((size_t)((ntb + nt) * 16 + (k0 >> 5)) * 8 + g * 2) * 128 + cl * 8;
            bh0[nt].v = *(const bf8v*)(wp + be);
            bl0[nt].v = *(const bf8v*)(wp + be + 128);
        }
        __syncthreads();
        {
            unsigned int h0, l0, h1, l1;
            split_pair(xl0.x, xl0.y, h0, l0);
            split_pair(xl0.z, xl0.w, h1, l1);
            *(uint2*)(alw + g2b * 256) = make_uint2(h0, h1);
            *(uint2*)(alw + g2b * 256 + 128) = make_uint2(l0, l1);
            split_pair(xl1.x, xl1.y, h0, l0);
            split_pair(xl1.z, xl1.w, h1, l1);
            *(uint2*)(alw + (g2b + 1) * 256) = make_uint2(h0, h1);
            *(uint2*)(alw + (g2b + 1) * 256 + 128) = make_uint2(l0, l1);
        }
        __syncthreads();
        AFrag bh1[4], bl1[4];
#pragma unroll
        for (int nt = 0; nt < 4; ++nt) {
            const size_t be = ((size_t)((ntb + nt) * 16 + (k0 >> 5) + 1) * 8 + g * 2) * 128 + cl * 8;
            bh1[nt].v = *(const bf8v*)(wp + be);
            bl1[nt].v = *(const bf8v*)(wp + be + 128);
        }
#pragma unroll
        for (int ks = 0; ks < 2; ++ks) {
            AFrag ah, alo;
            {
                short* ap = Al + ks * 2048 + wr * 1024 + g * 256 + cl * 8;
                ah.v = *(const bf8v*)ap;
                alo.v = *(const bf8v*)(ap + 128);
            }
#pragma unroll
            for (int nt = 0; nt < 4; ++nt) {
                const AFrag& bhf = ks ? bh1[nt] : bh0[nt];
                const AFrag& blf = ks ? bl1[nt] : bl0[nt];
                acc[nt] = __builtin_amdgcn_mfma_f32_16x16x32_bf16(ah.v, bhf.v, acc[nt], 0, 0, 0);
                acc[nt] = __builtin_amdgcn_mfma_f32_16x16x32_bf16(alo.v, bhf.v, acc[nt], 0, 0, 0);
                acc[nt] = __builtin_amdgcn_mfma_f32_16x16x32_bf16(ah.v, blf.v, acc[nt], 0, 0, 0);
            }
        }
    }
    const int mbase = m0 + wr * 16;
    const int nb = n0 + wc * 64;
#pragma unroll
    for (int nt = 0; nt < 4; ++nt) {
        const int n = nb + nt * 16 + cl;
        const float bb = bias[n];
#pragma unroll
        for (int r = 0; r < 4; ++r) {
            const int m = mbase + 4 * g + r;
            outp[(size_t)m * 512 + n] = acc[nt][r] + bb;
        }
    }
}

// ---------------------------------------------------------------------------
// K3: LDS-staged streaming MFMA attention (unchanged from round 6).
// ---------------------------------------------------------------------------
__global__ __launch_bounds__(256, 2) void k_attn(
    const unsigned short* __restrict__ qb_g, const unsigned short* __restrict__ kb_g,
    const unsigned short* __restrict__ vt_g, const unsigned short* __restrict__ wgc,
    float* __restrict__ ao)
{
    const int bid = blockIdx.x;
    const int lid = ((bid & 7) << 6) | (bid >> 3);
    const int qt = lid & 7;
    const int h = (lid >> 3) & 7;
    const int b = lid >> 6;
    const int bh = b * H_ + h;

    const int t = threadIdx.x;
    const int lane = t & 63;
    const int w = t >> 6;
    const int cl = lane & 15;
    const int g = lane >> 4;

    __shared__ __align__(16) short Kf[4][2][64][8];
    __shared__ __align__(16) short Vf[2][4][64][8];
    __shared__ __align__(16) short Wf[4][4][64][4];

    AFrag qf0, qf1;
    {
        const unsigned short* qrow = qb_g + ((size_t)bh * N_ + qt * 64 + w * 16 + cl) * DK_;
        qf0.d[0] = *(const uint2*)&qrow[4 * g];
        qf0.d[1] = *(const uint2*)&qrow[16 + 4 * g];
        qf1.d[0] = *(const uint2*)&qrow[32 + 4 * g];
        qf1.d[1] = *(const uint2*)&qrow[48 + 4 * g];
    }

    const unsigned short* kb_bh = kb_g + (size_t)bh * N_ * DK_;
    const unsigned short* vt_bh = vt_g + (size_t)bh * DK_ * N_;
    const unsigned short* wg_q  = wgc + ((size_t)bh * N_ + qt * 64) * N_;

    const int sr = t >> 2;
    const int sc = t & 3;

#define LOADC(mc)                                                               \
    pfa = *(const uint4*)(kb_bh + (size_t)((mc) + sr) * 64 + sc * 8);           \
    pfb = *(const uint4*)(kb_bh + (size_t)((mc) + sr) * 64 + sc * 8 + 32);      \
    pfc = *(const uint4*)(vt_bh + (size_t)sr * 512 + (mc) + sc * 8);            \
    pfd = *(const uint4*)(vt_bh + (size_t)sr * 512 + (mc) + sc * 8 + 32);       \
    pfe = *(const uint4*)(wg_q + (size_t)sr * 512 + (mc) + sc * 8);             \
    pff = *(const uint4*)(wg_q + (size_t)sr * 512 + (mc) + sc * 8 + 32);

#define STK(v, ci) {                                                            \
    short* d = &Kf[sr >> 4][(ci) >> 2][(sr & 15) + (((ci) & 1) << 5)]           \
                 [(((ci) >> 1) & 1) * 4];                                       \
    *(uint2*)d = make_uint2((v).x, (v).y);                                      \
    *(uint2*)(d + 128) = make_uint2((v).z, (v).w); }
#define STV(v, ci) {                                                            \
    short* d = &Vf[(ci) >> 2][sr >> 4][(sr & 15) + (((ci) & 1) << 5)]           \
                 [(((ci) >> 1) & 1) * 4];                                       \
    *(uint2*)d = make_uint2((v).x, (v).y);                                      \
    *(uint2*)(d + 128) = make_uint2((v).z, (v).w); }
#define STW(v, ci) {                                                            \
    short* d = &Wf[(ci) >> 1][sr >> 4][(sr & 15) + (((ci) & 1) << 5)][0];       \
    *(uint2*)d = make_uint2((v).x, (v).y);                                      \
    *(uint2*)(d + 64) = make_uint2((v).z, (v).w); }

    uint4 pfa, pfb, pfc, pfd, pfe, pff;
    LOADC(0)

    float rsum = 0.f;
    f4v oacc[4] = {(f4v){0.f, 0.f, 0.f, 0.f}, (f4v){0.f, 0.f, 0.f, 0.f},
                   (f4v){0.f, 0.f, 0.f, 0.f}, (f4v){0.f, 0.f, 0.f, 0.f}};

    for (int c = 0; c < 8; ++c) {
        __syncthreads();
        STK(pfa, sc)  STK(pfb, sc + 4)
        STV(pfc, sc)  STV(pfd, sc + 4)
        STW(pfe, sc)  STW(pff, sc + 4)
        __syncthreads();
        if (c < 7) { LOADC((c + 1) * 64) }

#pragma unroll
        for (int hf = 0; hf < 2; ++hf) {
            const bf8v a00 = *(const bf8v*)&Kf[2 * hf][0][lane][0];
            const bf8v a01 = *(const bf8v*)&Kf[2 * hf][1][lane][0];
            const bf8v a10 = *(const bf8v*)&Kf[2 * hf + 1][0][lane][0];
            const bf8v a11 = *(const bf8v*)&Kf[2 * hf + 1][1][lane][0];
            f4v sv0 = __builtin_amdgcn_mfma_f32_16x16x32_bf16(
                a00, qf0.v, (f4v){0.f, 0.f, 0.f, 0.f}, 0, 0, 0);
            sv0 = __builtin_amdgcn_mfma_f32_16x16x32_bf16(a01, qf1.v, sv0, 0, 0, 0);
            f4v sv1 = __builtin_amdgcn_mfma_f32_16x16x32_bf16(
                a10, qf0.v, (f4v){0.f, 0.f, 0.f, 0.f}, 0, 0, 0);
            sv1 = __builtin_amdgcn_mfma_f32_16x16x32_bf16(a11, qf1.v, sv1, 0, 0, 0);

            const uint2 wg0 = *(const uint2*)&Wf[2 * hf][w][lane][0];
            const uint2 wg1 = *(const uint2*)&Wf[2 * hf + 1][w][lane][0];
            float p[8];
            p[0] = bf2f((unsigned short)wg0.x) * __expf(sv0[0]);
            p[1] = bf2f((unsigned short)(wg0.x >> 16)) * __expf(sv0[1]);
            p[2] = bf2f((unsigned short)wg0.y) * __expf(sv0[2]);
            p[3] = bf2f((unsigned short)(wg0.y >> 16)) * __expf(sv0[3]);
            p[4] = bf2f((unsigned short)wg1.x) * __expf(sv1[0]);
            p[5] = bf2f((unsigned short)(wg1.x >> 16)) * __expf(sv1[1]);
            p[6] = bf2f((unsigned short)wg1.y) * __expf(sv1[2]);
            p[7] = bf2f((unsigned short)(wg1.y >> 16)) * __expf(sv1[3]);
            rsum += p[0] + p[1] + p[2] + p[3] + p[4] + p[5] + p[6] + p[7];

            AFrag pa;
            pa.u[0] = cvt_pk_bf16(p[0], p[1]);
            pa.u[1] = cvt_pk_bf16(p[2], p[3]);
            pa.u[2] = cvt_pk_bf16(p[4], p[5]);
            pa.u[3] = cvt_pk_bf16(p[6], p[7]);

#pragma unroll
            for (int db = 0; db < 4; ++db) {
                const bf8v vb = *(const bf8v*)&Vf[hf][db][lane][0];
                oacc[db] = __builtin_amdgcn_mfma_f32_16x16x32_bf16(
                    pa.v, vb, oacc[db], 0, 0, 0);
            }
        }
    }

    rsum += __shfl_xor(rsum, 16);
    rsum += __shfl_xor(rsum, 32);

    float rinv[4];
#pragma unroll
    for (int r = 0; r < 4; ++r) rinv[r] = 1.0f / __shfl(rsum, 4 * g + r);

    const int q0 = qt * 64 + w * 16;
#pragma unroll
    for (int db = 0; db < 4; ++db) {
#pragma unroll
        for (int r = 0; r < 4; ++r) {
            const int qq = q0 + 4 * g + r;
            ao[((size_t)(b * N_ + qq)) * D_ + h * DK_ + db * 16 + cl] = oacc[db][r] * rinv[r];
        }
    }
#undef LOADC
#undef STK
#undef STV
#undef STW
}

extern "C" void kernel_launch(void* const* d_in, const int* in_sizes, int n_in,
                              void* d_out, int out_size, void* d_ws, size_t ws_size,
                              hipStream_t stream) {
    (void)in_sizes; (void)n_in; (void)out_size; (void)ws_size;

    const float* xq  = (const float*)d_in[0];
    const float* xk  = (const float*)d_in[1];
    const float* xv  = (const float*)d_in[2];
    const float* box = (const float*)d_in[3];
    const float* Wq  = (const float*)d_in[4];
    const float* bq  = (const float*)d_in[5];
    const float* Wk  = (const float*)d_in[6];
    const float* bk  = (const float*)d_in[7];
    const float* Wv  = (const float*)d_in[8];
    const float* bv  = (const float*)d_in[9];
    const float* Wo  = (const float*)d_in[10];
    const float* bo  = (const float*)d_in[11];
    const float* WGw = (const float*)d_in[12];
    const float* WGb = (const float*)d_in[13];

    // ws: qb 4M | kb 4M | vt 4M | wgc 32M | ao 8M (f32) | whl 3M  = 55 MiB
    unsigned short* qb  = (unsigned short*)d_ws;
    unsigned short* kb  = qb + (1u << 21);
    unsigned short* vt  = kb + (1u << 21);
    unsigned short* wgc = vt + (1u << 21);
    float* ao = (float*)((char*)d_ws + (44u << 20));
    unsigned short* whl = (unsigned short*)((char*)d_ws + (52u << 20));

    k_split_w<<<dim3(32, 4), 256, 0, stream>>>(Wq, Wk, Wv, Wo, whl);
    k_mix<<<dim3(4864), 256, 0, stream>>>(xq, xk, xv, whl, bq, bk, bv, qb, kb, vt,
                                          box, WGw, WGb, wgc);
    k_attn<<<dim3(512), 256, 0, stream>>>(qb, kb, vt, wgc, ao);
    k_gemm_o<<<dim3(128, 4), 256, 0, stream>>>(ao, whl, bo, (float*)d_out);
}

// Round 12
// 81.076 us; speedup vs baseline: 1.3351x; 1.3351x over previous
//
#include <hip/hip_runtime.h>
#include <hip/hip_bf16.h>

#define B_ 8
#define N_ 512
#define D_ 512
#define H_ 8
#define DK_ 64

// 1000^(-f/8), f=0..7 (double-evaluated, f32-rounded)
__device__ constexpr float DMc[8] = {
    1.0f, 0.42169650342905464f, 0.1778279410038923f, 0.07498942093324559f,
    0.03162277660168379f, 0.013335214321633241f, 0.005623413251903491f,
    0.0023713737056616554f};

__device__ inline float bf2f(unsigned short u) {
    unsigned int x = ((unsigned int)u) << 16;
    return __uint_as_float(x);
}

typedef __attribute__((ext_vector_type(8))) short bf8v;
typedef __attribute__((ext_vector_type(4))) float f4v;

union AFrag { bf8v v; unsigned int u[4]; uint2 d[2]; };

__device__ inline unsigned int cvt_pk_bf16(float a, float b) {
    unsigned int r;
    asm("v_cvt_pk_bf16_f32 %0, %1, %2" : "=v"(r) : "v"(a), "v"(b));
    return r;  // bits[15:0]=bf16(a), bits[31:16]=bf16(b)
}

// x = hi + lo (both bf16), fp32-accurate reconstruction for split-MFMA
__device__ inline void split_pair(float a, float b, unsigned int& uhi, unsigned int& ulo) {
    const unsigned int uh = cvt_pk_bf16(a, b);
    const float ah = __uint_as_float(uh << 16);
    const float bh = __uint_as_float(uh & 0xFFFF0000u);
    ulo = cvt_pk_bf16(a - ah, b - bh);
    uhi = uh;
}

// ---------------------------------------------------------------------------
// K0: pre-convert weights to frag-major planes.
// z=0,1 (Wq,Wk): bf16 plane [nt32][ks16][g4][row16][8] -> whl + z*262144.
// z=2,3 (Wv,Wo): hi/lo planes [nt32][ks16][g4][hl2][row16][8] -> whl+524288+...
// ---------------------------------------------------------------------------
__global__ __launch_bounds__(256) void k_split_w(
    const float* __restrict__ Wq, const float* __restrict__ Wk,
    const float* __restrict__ Wv, const float* __restrict__ Wo,
    unsigned short* __restrict__ whl)
{
    const int z = blockIdx.y;
    const float* W = (z == 0) ? Wq : (z == 1) ? Wk : (z == 2) ? Wv : Wo;

    const int nt = blockIdx.x;        // ntile 0..31
    const int t = threadIdx.x;
    const int row = t >> 4;           // 0..15
    const int ks = t & 15;

    const float* wsrc = W + (size_t)(nt * 16 + row) * 512 + ks * 32;
    float e[32];
#pragma unroll
    for (int i = 0; i < 8; ++i) {
        const float4 v4 = *(const float4*)(wsrc + 4 * i);
        e[4 * i] = v4.x; e[4 * i + 1] = v4.y; e[4 * i + 2] = v4.z; e[4 * i + 3] = v4.w;
    }

    if (z < 2) {
        unsigned short* out = whl + (size_t)z * 262144;
#pragma unroll
        for (int g = 0; g < 4; ++g) {
            const unsigned int u0 = cvt_pk_bf16(e[4 * g + 0], e[4 * g + 1]);
            const unsigned int u1 = cvt_pk_bf16(e[4 * g + 2], e[4 * g + 3]);
            const unsigned int u2 = cvt_pk_bf16(e[16 + 4 * g + 0], e[16 + 4 * g + 1]);
            const unsigned int u3 = cvt_pk_bf16(e[16 + 4 * g + 2], e[16 + 4 * g + 3]);
            const size_t base = ((size_t)((nt * 16 + ks) * 4 + g)) * 128 + row * 8;
            *(uint4*)(out + base) = make_uint4(u0, u1, u2, u3);
        }
    } else {
        unsigned short* out = whl + 524288 + (size_t)(z - 2) * 524288;
#pragma unroll
        for (int g = 0; g < 4; ++g) {
            unsigned int h0, l0, h1, l1, h2, l2, h3, l3;
            split_pair(e[4 * g + 0], e[4 * g + 1], h0, l0);
            split_pair(e[4 * g + 2], e[4 * g + 3], h1, l1);
            split_pair(e[16 + 4 * g + 0], e[16 + 4 * g + 1], h2, l2);
            split_pair(e[16 + 4 * g + 2], e[16 + 4 * g + 3], h3, l3);
            const size_t base = ((size_t)(nt * 16 + ks) * 8 + g * 2) * 128 + row * 8;
            *(uint4*)(out + base) = make_uint4(h0, h1, h2, h3);
            *(uint4*)(out + base + 128) = make_uint4(l0, l1, l2, l3);
        }
    }
}

// ---------------------------------------------------------------------------
// K1 (r12): MERGED qkv-GEMM + box-gate. Grid 4864 = 256 groups x 19.
// gemm path: r9's LDS-staged form (proven 55us @ LB4, VGPR 64, no spill).
// wgc path: reg-hoisted S reads + __sincosf (proven bit-identical r10/r11).
// LB(256,4). LEDGER: LB6 => scratch spill (r8/r11); in-lane A-cvt => 16-line
// gathers, FETCH +15MB (r11); xb precompute => +6us split_w tax (r10).
// ---------------------------------------------------------------------------
__global__ __launch_bounds__(256, 4) void k_mix(
    const float* __restrict__ Xq, const float* __restrict__ Xk, const float* __restrict__ Xv,
    const unsigned short* __restrict__ whl,
    const float* __restrict__ bq, const float* __restrict__ bk, const float* __restrict__ bv,
    unsigned short* __restrict__ oq, unsigned short* __restrict__ ok,
    unsigned short* __restrict__ ov,
    const float* __restrict__ box, const float* __restrict__ WGw,
    const float* __restrict__ WGb, unsigned short* __restrict__ wgc)
{
    __shared__ __align__(16) char smem[8448];   // max(gemm 8192B, wgc 8320B)

    const int bid = blockIdx.x;
    const int grp = bid / 19;
    const int r19 = bid - grp * 19;
    const int t = threadIdx.x;

    if (r19 < 3) {
        // ---------------- GEMM path (LDS-staged, r9-proven) ----------------
        const int gid = grp * 3 + r19;      // 0..767
        const int zz = gid % 3;
        const int mn = gid / 3;             // 0..255
        const int m0 = (mn & 63) * 64;
        const int n0 = (mn >> 6) * 128;

        const float* X = (zz == 0) ? Xq : (zz == 1) ? Xk : Xv;
        const float* bias = (zz == 0) ? bq : (zz == 1) ? bk : bv;
        const unsigned short* wp = whl + ((zz == 2) ? 524288 : (size_t)zz * 262144);
        const bool vsplit = (zz == 2);

        short* Al = (short*)smem;           // [ks2][mt4][g4][row16][8] shorts

        const int lane = t & 63;
        const int wv = t >> 6;
        const int cl = lane & 15, g = lane >> 4;
        const int wr = wv >> 1, wc = wv & 1;
        const int srow = t >> 2;
        const int skq = t & 3;
        const float* xp = X + (size_t)(m0 + srow) * 512 + skq * 16;
        short* alw = Al + (skq >> 1) * 2048 + (srow >> 4) * 512 + (srow & 15) * 8 +
                     (skq & 1) * 4;

        f4v acc[2][4];
#pragma unroll
        for (int i = 0; i < 2; ++i)
#pragma unroll
            for (int j = 0; j < 4; ++j) acc[i][j] = (f4v){0.f, 0.f, 0.f, 0.f};
        const int ntb = (n0 >> 4) + wc * 4;

        for (int k0 = 0; k0 < 512; k0 += 64) {
            float4 xl[4];
#pragma unroll
            for (int i = 0; i < 4; ++i) xl[i] = *(const float4*)(xp + k0 + 4 * i);

            AFrag bh0[4], bl0[4];
#pragma unroll
            for (int nt = 0; nt < 4; ++nt) {
                if (vsplit) {
                    const size_t be = ((size_t)((ntb + nt) * 16 + (k0 >> 5)) * 8 + g * 2) * 128 +
                                      cl * 8;
                    bh0[nt].v = *(const bf8v*)(wp + be);
                    bl0[nt].v = *(const bf8v*)(wp + be + 128);
                } else {
                    const size_t be = ((size_t)((ntb + nt) * 16 + (k0 >> 5)) * 4 + g) * 128 +
                                      cl * 8;
                    bh0[nt].v = *(const bf8v*)(wp + be);
                }
            }
            __syncthreads();
            {
                float xe[16];
#pragma unroll
                for (int i = 0; i < 4; ++i) {
                    xe[4 * i] = xl[i].x; xe[4 * i + 1] = xl[i].y;
                    xe[4 * i + 2] = xl[i].z; xe[4 * i + 3] = xl[i].w;
                }
#pragma unroll
                for (int g2 = 0; g2 < 4; ++g2) {
                    const unsigned int u0 = cvt_pk_bf16(xe[4 * g2 + 0], xe[4 * g2 + 1]);
                    const unsigned int u1 = cvt_pk_bf16(xe[4 * g2 + 2], xe[4 * g2 + 3]);
                    *(uint2*)(alw + g2 * 128) = make_uint2(u0, u1);
                }
            }
            __syncthreads();
            AFrag bh1[4], bl1[4];
#pragma unroll
            for (int nt = 0; nt < 4; ++nt) {
                if (vsplit) {
                    const size_t be = ((size_t)((ntb + nt) * 16 + (k0 >> 5) + 1) * 8 + g * 2) * 128 +
                                      cl * 8;
                    bh1[nt].v = *(const bf8v*)(wp + be);
                    bl1[nt].v = *(const bf8v*)(wp + be + 128);
                } else {
                    const size_t be = ((size_t)((ntb + nt) * 16 + (k0 >> 5) + 1) * 4 + g) * 128 +
                                      cl * 8;
                    bh1[nt].v = *(const bf8v*)(wp + be);
                }
            }
#pragma unroll
            for (int ks = 0; ks < 2; ++ks) {
                AFrag ah[2];
#pragma unroll
                for (int mt = 0; mt < 2; ++mt)
                    ah[mt].v = *(const bf8v*)(Al + ks * 2048 + (wr * 2 + mt) * 512 +
                                              g * 128 + cl * 8);
#pragma unroll
                for (int nt = 0; nt < 4; ++nt) {
                    const AFrag& bhf = ks ? bh1[nt] : bh0[nt];
#pragma unroll
                    for (int mt = 0; mt < 2; ++mt)
                        acc[mt][nt] = __builtin_amdgcn_mfma_f32_16x16x32_bf16(
                            ah[mt].v, bhf.v, acc[mt][nt], 0, 0, 0);
                    if (vsplit) {
                        const AFrag& blf = ks ? bl1[nt] : bl0[nt];
#pragma unroll
                        for (int mt = 0; mt < 2; ++mt)
                            acc[mt][nt] = __builtin_amdgcn_mfma_f32_16x16x32_bf16(
                                ah[mt].v, blf.v, acc[mt][nt], 0, 0, 0);
                    }
                }
            }
        }

        const int mbase = m0 + wr * 32;
        const int nb = n0 + wc * 64;

        if (zz == 2) {
#pragma unroll
            for (int mt = 0; mt < 2; ++mt) {
#pragma unroll
                for (int nt = 0; nt < 4; ++nt) {
                    const int m = mbase + mt * 16 + 4 * g;
                    const int n = nb + nt * 16 + cl;
                    const float bb = bias[n];
                    uint2 pk;
                    pk.x = cvt_pk_bf16(acc[mt][nt][0] + bb, acc[mt][nt][1] + bb);
                    pk.y = cvt_pk_bf16(acc[mt][nt][2] + bb, acc[mt][nt][3] + bb);
                    *(uint2*)&ov[(((size_t)(m >> 9) * 8 + (n >> 6)) * 64 + (n & 63)) * 512 +
                                 (m & 511)] = pk;
                }
            }
        } else {
            unsigned short* outp = (zz == 0) ? oq : ok;
            const float sc = (zz == 0) ? 0.125f : 1.0f;
#pragma unroll
            for (int mt = 0; mt < 2; ++mt) {
#pragma unroll
                for (int nt = 0; nt < 4; ++nt) {
                    const int n = nb + nt * 16 + cl;
                    const float bb = bias[n];
#pragma unroll
                    for (int r = 0; r < 4; ++r) {
                        const int m = mbase + mt * 16 + 4 * g + r;
                        outp[(((size_t)(m >> 9) * 8 + (n >> 6)) * 512 + (m & 511)) * 64 +
                             (n & 63)] =
                            (unsigned short)cvt_pk_bf16((acc[mt][nt][r] + bb) * sc, 0.f);
                    }
                }
            }
        }
    } else {
        // ---------------- WGC path ----------------
        const int wb = grp * 16 + (r19 - 3);   // 0..4095
        const int n = wb & 511;
        const int b = wb >> 9;

        float (*S)[520] = (float(*)[520])smem;

        for (int mi = t; mi < 512; mi += 256) {
            const float4 bx = *(const float4*)&box[(size_t)(b * N_ + mi) * 4];
            S[0][mi] = (bx.x + bx.z) * 0.5f;
            S[1][mi] = (bx.y + bx.w) * 0.5f;
            S[2][mi] = __logf(bx.z - bx.x + 1.0f);
            S[3][mi] = __logf(bx.w - bx.y + 1.0f);
        }

        const float4 bn = *(const float4*)&box[(size_t)(b * N_ + n) * 4];
        const float wn = bn.z - bn.x + 1.0f;
        const float hn = bn.w - bn.y + 1.0f;
        const float rwn = 1.0f / wn;
        const float rhn = 1.0f / hn;
        const float cxn = (bn.x + bn.z) * 0.5f;
        const float cyn = (bn.y + bn.w) * 0.5f;
        const float lwn = __logf(wn);
        const float lhn = __logf(hn);

        const int lane = t & 63;
        const int col = lane & 15;
        const int grp2 = lane >> 4;
        const int w = t >> 6;

        AFrag bs, bc;
        if (col < 8) {
            const float* wr2 = WGw + col * 64 + grp2 * 8;
#pragma unroll
            for (int j = 0; j < 4; ++j) {
                bs.u[j] = cvt_pk_bf16(wr2[2 * j], wr2[2 * j + 1]);
                bc.u[j] = cvt_pk_bf16(wr2[32 + 2 * j], wr2[32 + 2 * j + 1]);
            }
        } else {
#pragma unroll
            for (int j = 0; j < 4; ++j) { bs.u[j] = 0u; bc.u[j] = 0u; }
        }
        const float bias = (col < 8) ? WGb[col] : 0.0f;

        const float dn = (grp2 == 0) ? cxn : (grp2 == 1) ? cyn : (grp2 == 2) ? lwn : lhn;
        const float rA = (grp2 == 0) ? rwn : rhn;

        unsigned short* outb = (col < 8)
            ? wgc + ((size_t)(b * H_ + col) * N_ + n) * N_ : wgc;

        __syncthreads();

        // hoist: this lane's 8 table values -> registers; loop is memory-free
        float svr[8];
#pragma unroll
        for (int mt = 0; mt < 8; ++mt) svr[mt] = S[grp2][mt * 64 + w * 16 + col];

#pragma unroll
        for (int mt = 0; mt < 8; ++mt) {
            const int m0 = mt * 64 + w * 16;

            const float diff = dn - svr[mt];
            const float posA = __logf(fmaxf(fabsf(diff) * rA, 1e-3f));
            const float pos = (grp2 < 2) ? posA : diff;
            const float p100 = 100.0f * pos;

            float sn[8], cs[8];
#pragma unroll
            for (int j = 0; j < 8; ++j) {
                __sincosf(p100 * DMc[j], &sn[j], &cs[j]);
            }
            AFrag as_, ac_;
#pragma unroll
            for (int j = 0; j < 4; ++j) {
                as_.u[j] = cvt_pk_bf16(sn[2 * j], sn[2 * j + 1]);
                ac_.u[j] = cvt_pk_bf16(cs[2 * j], cs[2 * j + 1]);
            }

            f4v acc = __builtin_amdgcn_mfma_f32_16x16x32_bf16(
                as_.v, bs.v, (f4v){0.f, 0.f, 0.f, 0.f}, 0, 0, 0);
            acc = __builtin_amdgcn_mfma_f32_16x16x32_bf16(ac_.v, bc.v, acc, 0, 0, 0);

            if (col < 8) {
                const int mrow = m0 + grp2 * 4;
                const float v0 = fmaxf(acc[0] + bias, 1e-6f);
                const float v1 = fmaxf(acc[1] + bias, 1e-6f);
                const float v2 = fmaxf(acc[2] + bias, 1e-6f);
                const float v3 = fmaxf(acc[3] + bias, 1e-6f);
                uint2 pk;
                pk.x = cvt_pk_bf16(v0, v1);
                pk.y = cvt_pk_bf16(v2, v3);
                *(uint2*)&outb[mrow] = pk;
            }
        }
    }
}

// ---------------------------------------------------------------------------
// K4: output projection, 32x128 tiles, 3-term split (r9-proven).
// ---------------------------------------------------------------------------
__global__ __launch_bounds__(256, 2) void k_gemm_o(
    const float* __restrict__ AO, const unsigned short* __restrict__ whl,
    const float* __restrict__ bias, float* __restrict__ outp)
{
    const unsigned short* wp = whl + 1048576;   // Wo hi/lo plane

    const int m0 = blockIdx.x * 32;
    const int n0 = blockIdx.y * 128;
    __shared__ __align__(16) short Al[4096];    // [ks2][mt2][g4][hl2][row16][8]
    const int t = threadIdx.x;
    const int lane = t & 63;
    const int wv = t >> 6;
    const int cl = lane & 15, g = lane >> 4;
    const int wr = wv >> 1, wc = wv & 1;

    const int srow = t >> 3;        // 0..31
    const int skq = t & 7;
    const int ksub = skq >> 2;
    const int half = (skq >> 1) & 1;
    const int g2b = (skq & 1) * 2;
    const float* xp = AO + (size_t)(m0 + srow) * 512 + skq * 8;
    short* alw = Al + ksub * 2048 + (srow >> 4) * 1024 + (srow & 15) * 8 + half * 4;

    f4v acc[4];
#pragma unroll
    for (int j = 0; j < 4; ++j) acc[j] = (f4v){0.f, 0.f, 0.f, 0.f};
    const int ntb = (n0 >> 4) + wc * 4;

    for (int k0 = 0; k0 < 512; k0 += 64) {
        float4 xl0 = *(const float4*)(xp + k0);
        float4 xl1 = *(const float4*)(xp + k0 + 4);

        AFrag bh0[4], bl0[4];
#pragma unroll
        for (int nt = 0; nt < 4; ++nt) {
            const size_t be = ((size_t)((ntb + nt) * 16 + (k0 >> 5)) * 8 + g * 2) * 128 + cl * 8;
            bh0[nt].v = *(const bf8v*)(wp + be);
            bl0[nt].v = *(const bf8v*)(wp + be + 128);
        }
        __syncthreads();
        {
            unsigned int h0, l0, h1, l1;
            split_pair(xl0.x, xl0.y, h0, l0);
            split_pair(xl0.z, xl0.w, h1, l1);
            *(uint2*)(alw + g2b * 256) = make_uint2(h0, h1);
            *(uint2*)(alw + g2b * 256 + 128) = make_uint2(l0, l1);
            split_pair(xl1.x, xl1.y, h0, l0);
            split_pair(xl1.z, xl1.w, h1, l1);
            *(uint2*)(alw + (g2b + 1) * 256) = make_uint2(h0, h1);
            *(uint2*)(alw + (g2b + 1) * 256 + 128) = make_uint2(l0, l1);
        }
        __syncthreads();
        AFrag bh1[4], bl1[4];
#pragma unroll
        for (int nt = 0; nt < 4; ++nt) {
            const size_t be = ((size_t)((ntb + nt) * 16 + (k0 >> 5) + 1) * 8 + g * 2) * 128 + cl * 8;
            bh1[nt].v = *(const bf8v*)(wp + be);
            bl1[nt].v = *(const bf8v*)(wp + be + 128);
        }
#pragma unroll
        for (int ks = 0; ks < 2; ++ks) {
            AFrag ah, alo;
            {
                short* ap = Al + ks * 2048 + wr * 1024 + g * 256 + cl * 8;
                ah.v = *(const bf8v*)ap;
                alo.v = *(const bf8v*)(ap + 128);
            }
#pragma unroll
            for (int nt = 0; nt < 4; ++nt) {
                const AFrag& bhf = ks ? bh1[nt] : bh0[nt];
                const AFrag& blf = ks ? bl1[nt] : bl0[nt];
                acc[nt] = __builtin_amdgcn_mfma_f32_16x16x32_bf16(ah.v, bhf.v, acc[nt], 0, 0, 0);
                acc[nt] = __builtin_amdgcn_mfma_f32_16x16x32_bf16(alo.v, bhf.v, acc[nt], 0, 0, 0);
                acc[nt] = __builtin_amdgcn_mfma_f32_16x16x32_bf16(ah.v, blf.v, acc[nt], 0, 0, 0);
            }
        }
    }
    const int mbase = m0 + wr * 16;
    const int nb = n0 + wc * 64;
#pragma unroll
    for (int nt = 0; nt < 4; ++nt) {
        const int n = nb + nt * 16 + cl;
        const float bb = bias[n];
#pragma unroll
        for (int r = 0; r < 4; ++r) {
            const int m = mbase + 4 * g + r;
            outp[(size_t)m * 512 + n] = acc[nt][r] + bb;
        }
    }
}

// ---------------------------------------------------------------------------
// K3 (v5): LDS-staged streaming MFMA attention, DOUBLE-BUFFERED (T14).
// Per chunk: issue loads(c+1) -> compute(c) from buf[c&1] -> store(c+1) into
// buf[(c+1)&1] -> one barrier. Store-side vmcnt wait is covered by compute.
// LDS 40KB x 2 buffers-in-one; 2 blocks/CU (80KB).
// ---------------------------------------------------------------------------
__global__ __launch_bounds__(256, 2) void k_attn(
    const unsigned short* __restrict__ qb_g, const unsigned short* __restrict__ kb_g,
    const unsigned short* __restrict__ vt_g, const unsigned short* __restrict__ wgc,
    float* __restrict__ ao)
{
    const int bid = blockIdx.x;
    const int lid = ((bid & 7) << 6) | (bid >> 3);
    const int qt = lid & 7;
    const int h = (lid >> 3) & 7;
    const int b = lid >> 6;
    const int bh = b * H_ + h;

    const int t = threadIdx.x;
    const int lane = t & 63;
    const int w = t >> 6;
    const int cl = lane & 15;
    const int g = lane >> 4;

    __shared__ __align__(16) short Kf[2][4][2][64][8];   // 16KB
    __shared__ __align__(16) short Vf[2][2][4][64][8];   // 16KB
    __shared__ __align__(16) short Wf[2][4][4][64][4];   // 8KB

    AFrag qf0, qf1;
    {
        const unsigned short* qrow = qb_g + ((size_t)bh * N_ + qt * 64 + w * 16 + cl) * DK_;
        qf0.d[0] = *(const uint2*)&qrow[4 * g];
        qf0.d[1] = *(const uint2*)&qrow[16 + 4 * g];
        qf1.d[0] = *(const uint2*)&qrow[32 + 4 * g];
        qf1.d[1] = *(const uint2*)&qrow[48 + 4 * g];
    }

    const unsigned short* kb_bh = kb_g + (size_t)bh * N_ * DK_;
    const unsigned short* vt_bh = vt_g + (size_t)bh * DK_ * N_;
    const unsigned short* wg_q  = wgc + ((size_t)bh * N_ + qt * 64) * N_;

    const int sr = t >> 2;
    const int sc = t & 3;

#define LOADC(mc)                                                               \
    pfa = *(const uint4*)(kb_bh + (size_t)((mc) + sr) * 64 + sc * 8);           \
    pfb = *(const uint4*)(kb_bh + (size_t)((mc) + sr) * 64 + sc * 8 + 32);      \
    pfc = *(const uint4*)(vt_bh + (size_t)sr * 512 + (mc) + sc * 8);            \
    pfd = *(const uint4*)(vt_bh + (size_t)sr * 512 + (mc) + sc * 8 + 32);       \
    pfe = *(const uint4*)(wg_q + (size_t)sr * 512 + (mc) + sc * 8);             \
    pff = *(const uint4*)(wg_q + (size_t)sr * 512 + (mc) + sc * 8 + 32);

#define STK(B, v, ci) {                                                         \
    short* d = &Kf[B][sr >> 4][(ci) >> 2][(sr & 15) + (((ci) & 1) << 5)]        \
                 [(((ci) >> 1) & 1) * 4];                                       \
    *(uint2*)d = make_uint2((v).x, (v).y);                                      \
    *(uint2*)(d + 128) = make_uint2((v).z, (v).w); }
#define STV(B, v, ci) {                                                         \
    short* d = &Vf[B][(ci) >> 2][sr >> 4][(sr & 15) + (((ci) & 1) << 5)]        \
                 [(((ci) >> 1) & 1) * 4];                                       \
    *(uint2*)d = make_uint2((v).x, (v).y);                                      \
    *(uint2*)(d + 128) = make_uint2((v).z, (v).w); }
#define STW(B, v, ci) {                                                         \
    short* d = &Wf[B][(ci) >> 1][sr >> 4][(sr & 15) + (((ci) & 1) << 5)][0];    \
    *(uint2*)d = make_uint2((v).x, (v).y);                                      \
    *(uint2*)(d + 64) = make_uint2((v).z, (v).w); }

    uint4 pfa, pfb, pfc, pfd, pfe, pff;
    LOADC(0)
    STK(0, pfa, sc)  STK(0, pfb, sc + 4)
    STV(0, pfc, sc)  STV(0, pfd, sc + 4)
    STW(0, pfe, sc)  STW(0, pff, sc + 4)
    __syncthreads();

    float rsum = 0.f;
    f4v oacc[4] = {(f4v){0.f, 0.f, 0.f, 0.f}, (f4v){0.f, 0.f, 0.f, 0.f},
                   (f4v){0.f, 0.f, 0.f, 0.f}, (f4v){0.f, 0.f, 0.f, 0.f}};

    for (int c = 0; c < 8; ++c) {
        const int bb = c & 1;
        if (c < 7) { LOADC((c + 1) * 64) }   // issue early; latency hides under compute

#pragma unroll
        for (int hf = 0; hf < 2; ++hf) {
            const bf8v a00 = *(const bf8v*)&Kf[bb][2 * hf][0][lane][0];
            const bf8v a01 = *(const bf8v*)&Kf[bb][2 * hf][1][lane][0];
            const bf8v a10 = *(const bf8v*)&Kf[bb][2 * hf + 1][0][lane][0];
            const bf8v a11 = *(const bf8v*)&Kf[bb][2 * hf + 1][1][lane][0];
            f4v sv0 = __builtin_amdgcn_mfma_f32_16x16x32_bf16(
                a00, qf0.v, (f4v){0.f, 0.f, 0.f, 0.f}, 0, 0, 0);
            sv0 = __builtin_amdgcn_mfma_f32_16x16x32_bf16(a01, qf1.v, sv0, 0, 0, 0);
            f4v sv1 = __builtin_amdgcn_mfma_f32_16x16x32_bf16(
                a10, qf0.v, (f4v){0.f, 0.f, 0.f, 0.f}, 0, 0, 0);
            sv1 = __builtin_amdgcn_mfma_f32_16x16x32_bf16(a11, qf1.v, sv1, 0, 0, 0);

            const uint2 wg0 = *(const uint2*)&Wf[bb][2 * hf][w][lane][0];
            const uint2 wg1 = *(const uint2*)&Wf[bb][2 * hf + 1][w][lane][0];
            float p[8];
            p[0] = bf2f((unsigned short)wg0.x) * __expf(sv0[0]);
            p[1] = bf2f((unsigned short)(wg0.x >> 16)) * __expf(sv0[1]);
            p[2] = bf2f((unsigned short)wg0.y) * __expf(sv0[2]);
            p[3] = bf2f((unsigned short)(wg0.y >> 16)) * __expf(sv0[3]);
            p[4] = bf2f((unsigned short)wg1.x) * __expf(sv1[0]);
            p[5] = bf2f((unsigned short)(wg1.x >> 16)) * __expf(sv1[1]);
            p[6] = bf2f((unsigned short)wg1.y) * __expf(sv1[2]);
            p[7] = bf2f((unsigned short)(wg1.y >> 16)) * __expf(sv1[3]);
            rsum += p[0] + p[1] + p[2] + p[3] + p[4] + p[5] + p[6] + p[7];

            AFrag pa;
            pa.u[0] = cvt_pk_bf16(p[0], p[1]);
            pa.u[1] = cvt_pk_bf16(p[2], p[3]);
            pa.u[2] = cvt_pk_bf16(p[4], p[5]);
            pa.u[3] = cvt_pk_bf16(p[6], p[7]);

#pragma unroll
            for (int db = 0; db < 4; ++db) {
                const bf8v vb = *(const bf8v*)&Vf[bb][hf][db][lane][0];
                oacc[db] = __builtin_amdgcn_mfma_f32_16x16x32_bf16(
                    pa.v, vb, oacc[db], 0, 0, 0);
            }
        }

        if (c < 7) {
            const int nb2 = bb ^ 1;
            STK(nb2, pfa, sc)  STK(nb2, pfb, sc + 4)
            STV(nb2, pfc, sc)  STV(nb2, pfd, sc + 4)
            STW(nb2, pfe, sc)  STW(nb2, pff, sc + 4)
        }
        __syncthreads();
    }

    rsum += __shfl_xor(rsum, 16);
    rsum += __shfl_xor(rsum, 32);

    float rinv[4];
#pragma unroll
    for (int r = 0; r < 4; ++r) rinv[r] = 1.0f / __shfl(rsum, 4 * g + r);

    const int q0 = qt * 64 + w * 16;
#pragma unroll
    for (int db = 0; db < 4; ++db) {
#pragma unroll
        for (int r = 0; r < 4; ++r) {
            const int qq = q0 + 4 * g + r;
            ao[((size_t)(b * N_ + qq)) * D_ + h * DK_ + db * 16 + cl] = oacc[db][r] * rinv[r];
        }
    }
#undef LOADC
#undef STK
#undef STV
#undef STW
}

extern "C" void kernel_launch(void* const* d_in, const int* in_sizes, int n_in,
                              void* d_out, int out_size, void* d_ws, size_t ws_size,
                              hipStream_t stream) {
    (void)in_sizes; (void)n_in; (void)out_size; (void)ws_size;

    const float* xq  = (const float*)d_in[0];
    const float* xk  = (const float*)d_in[1];
    const float* xv  = (const float*)d_in[2];
    const float* box = (const float*)d_in[3];
    const float* Wq  = (const float*)d_in[4];
    const float* bq  = (const float*)d_in[5];
    const float* Wk  = (const float*)d_in[6];
    const float* bk  = (const float*)d_in[7];
    const float* Wv  = (const float*)d_in[8];
    const float* bv  = (const float*)d_in[9];
    const float* Wo  = (const float*)d_in[10];
    const float* bo  = (const float*)d_in[11];
    const float* WGw = (const float*)d_in[12];
    const float* WGb = (const float*)d_in[13];

    // ws: qb 4M | kb 4M | vt 4M | wgc 32M | ao 8M (f32) | whl 3M  = 55 MiB
    unsigned short* qb  = (unsigned short*)d_ws;
    unsigned short* kb  = qb + (1u << 21);
    unsigned short* vt  = kb + (1u << 21);
    unsigned short* wgc = vt + (1u << 21);
    float* ao = (float*)((char*)d_ws + (44u << 20));
    unsigned short* whl = (unsigned short*)((char*)d_ws + (52u << 20));

    k_split_w<<<dim3(32, 4), 256, 0, stream>>>(Wq, Wk, Wv, Wo, whl);
    k_mix<<<dim3(4864), 256, 0, stream>>>(xq, xk, xv, whl, bq, bk, bv, qb, kb, vt,
                                          box, WGw, WGb, wgc);
    k_attn<<<dim3(512), 256, 0, stream>>>(qb, kb, vt, wgc, ao);
    k_gemm_o<<<dim3(128, 4), 256, 0, stream>>>(ao, whl, bo, (float*)d_out);
}